// Round 12
// baseline (431.784 us; speedup 1.0000x reference)
//
#include <hip/hip_runtime.h>
#include <hip/hip_bf16.h>
#include <math.h>

typedef __hip_bfloat16 bf16;
typedef __attribute__((ext_vector_type(8))) short short8;
typedef __attribute__((ext_vector_type(4))) short short4v;
typedef __attribute__((ext_vector_type(4))) float float4v;

static constexpr int cB  = 2;
static constexpr int cC  = 128;
static constexpr int cH  = 128;
static constexpr int cW  = 128;
static constexpr int cP  = cH * cW;       // 16384
static constexpr int cC3 = 384;
static constexpr int cHID = 340;
static constexpr int cNW = 1024;
static constexpr float cEPS = 1e-6f;

__device__ __forceinline__ float bfu2f(unsigned short u){
  union { unsigned int i; float f; } c; c.i = ((unsigned int)u) << 16; return c.f;
}
__device__ __forceinline__ unsigned short f2b(float f){
  union { float f; unsigned int u; } c; c.f = f;
  unsigned int r = c.u + 0x7FFFu + ((c.u >> 16) & 1u);
  return (unsigned short)(r >> 16);
}

// ---- convert all 8 weight matrices fp32 -> bf16 (with padding) into WB; tail zeroes S
__global__ void k_wcvt(const float* __restrict__ qkv_s, const float* __restrict__ qkv_c,
                       const float* __restrict__ fin_s, const float* __restrict__ fin_c,
                       const float* __restrict__ prj_s, const float* __restrict__ prj_c,
                       const float* __restrict__ fo_s,  const float* __restrict__ fo_c,
                       unsigned short* __restrict__ WB, float* __restrict__ S){
  int i = blockIdx.x * 256 + threadIdx.x;
  if (i >= 319488){
    int j = i - 319488;
    if (j < 8704) S[j] = 0.f;
    return;
  }
  float v;
  if (i < 98304){
    v = (i < 49152) ? qkv_s[i] : qkv_c[i - 49152];
  } else if (i < 196608){
    int j = (i < 147456) ? (i - 98304) : (i - 147456);
    int row = j >> 7, col = j & 127;
    const float* src = (i < 147456) ? fin_s : fin_c;
    v = (row < cHID) ? src[row * 128 + col] : 0.f;
  } else if (i < 229376){
    v = (i < 212992) ? prj_s[i - 196608] : prj_c[i - 212992];
  } else {
    int j = (i < 274432) ? (i - 229376) : (i - 274432);
    int row = j / 352, col = j - row * 352;
    const float* src = (i < 274432) ? fo_s : fo_c;
    v = (col < cHID) ? src[row * cHID + col] : 0.f;
  }
  WB[i] = f2b(v);
}

// ---- standalone LayerNorm (first LN only): fp32 [c][p] -> bf16 [p][128], roll shift
__global__ void __launch_bounds__(256) k_ln(const float* __restrict__ a,
                                            const float* __restrict__ gamma,
                                            const float* __restrict__ beta,
                                            unsigned short* __restrict__ out, int sh, int sw){
  int idx = blockIdx.x * 256 + threadIdx.x;
  if (idx >= cB * cP) return;
  int b = idx >> 14;
  int p = idx & (cP - 1);
  const float* ap = a + (size_t)b * cC * cP + p;
  float s = 0.f, ss = 0.f;
  #pragma unroll 8
  for (int c = 0; c < cC; c++){
    float v = ap[c * cP];
    s += v; ss += v * v;
  }
  float m = s * (1.f / cC);
  float var = ss * (1.f / cC) - m * m;
  float rstd = rsqrtf(var + cEPS);
  int h = p >> 7, w = p & 127;
  int h2 = (h + sh) & (cH - 1);
  int w2 = (w + sw) & (cW - 1);
  unsigned short* op = out + (size_t)b * cP * cC + (size_t)(h2 * cW + w2) * cC;
  #pragma unroll
  for (int c8 = 0; c8 < cC; c8 += 8){
    short8 tv;
    #pragma unroll
    for (int j = 0; j < 8; j++){
      float v = ap[(c8 + j) * cP];
      tv[j] = (short)f2b((v - m) * rstd * gamma[c8 + j] + beta[c8 + j]);
    }
    *(short8*)(op + c8) = tv;
  }
}

// ---- MFMA GEMM: 64px block, K=128 fully LDS-resident, m-loop over 3x128 tiles.
// X: [p][128] bf16; W: 384x128 bf16 (padded); out bf16 [p][m] pitch PM, guard wrow<PM.
__global__ void __launch_bounds__(256) k_gemm(const unsigned short* __restrict__ Wb,
                                              const unsigned short* __restrict__ Xg,
                                              unsigned short* __restrict__ Out,
                                              int PM){
  __shared__ short Xls[64 * 136];
  __shared__ short Wls[128 * 136];
  int b  = blockIdx.z;
  int p0 = blockIdx.x * 64;
  int t  = threadIdx.x;
  int lanelo = t & 15;
  int quad   = (t >> 4) & 3;
  int wv = t >> 6;
  int w1 = wv & 1;          // px half (32)
  int w2 = wv >> 1;         // m half (64)
  // stage X once
  {
    int row = t >> 2, kc = (t & 3) * 32;
    const unsigned short* src = Xg + (size_t)b * cP * 128 + (size_t)(p0 + row) * 128 + kc;
    short* dst = &Xls[row * 136 + kc];
    #pragma unroll
    for (int e = 0; e < 4; e++) *(short8*)(dst + e * 8) = *(const short8*)(src + e * 8);
  }
  unsigned short* Ob = Out + (size_t)b * cP * PM;
  for (int mt = 0; mt < 3; mt++){
    __syncthreads();           // prior m-tile frag reads done (covers X stage at mt=0)
    {
      int row = t >> 1, kc = (t & 1) * 64;
      const unsigned short* src = Wb + (size_t)(mt * 128 + row) * 128 + kc;
      short* dst = &Wls[row * 136 + kc];
      #pragma unroll
      for (int e = 0; e < 8; e++) *(short8*)(dst + e * 8) = *(const short8*)(src + e * 8);
    }
    __syncthreads();
    float4v acc[2][4];
    #pragma unroll
    for (int i = 0; i < 2; i++)
      #pragma unroll
      for (int j = 0; j < 4; j++)
        acc[i][j] = (float4v){0.f, 0.f, 0.f, 0.f};
    #pragma unroll
    for (int kk = 0; kk < 4; kk++){
      short8 af[2], bfr[4];
      #pragma unroll
      for (int i = 0; i < 2; i++)
        af[i] = *(const short8*)&Xls[(w1 * 32 + i * 16 + lanelo) * 136 + kk * 32 + quad * 8];
      #pragma unroll
      for (int j = 0; j < 4; j++)
        bfr[j] = *(const short8*)&Wls[(w2 * 64 + j * 16 + lanelo) * 136 + kk * 32 + quad * 8];
      #pragma unroll
      for (int i = 0; i < 2; i++)
        #pragma unroll
        for (int j = 0; j < 4; j++)
          acc[i][j] = __builtin_amdgcn_mfma_f32_16x16x32_bf16(af[i], bfr[j], acc[i][j], 0, 0, 0);
    }
    // D[pix][wrow]; pix = p0 + w1*32 + i*16 + quad*4 + r; wrow = mt*128 + w2*64 + j*16 + lanelo
    #pragma unroll
    for (int i = 0; i < 2; i++)
      #pragma unroll
      for (int j = 0; j < 4; j++){
        int wrow = mt * 128 + w2 * 64 + j * 16 + lanelo;
        if (wrow >= PM) continue;
        #pragma unroll
        for (int r = 0; r < 4; r++){
          int pix = p0 + w1 * 32 + i * 16 + quad * 4 + r;
          Ob[(size_t)pix * PM + wrow] = f2b(acc[i][j][r]);
        }
      }
  }
}

// ---- MFMA GEMM 64px x 128m (M=128) with fused epilogue.
// MODE 1: Tr = acc; LN(Base + acc) -> LNo   (proj+LN)
// MODE 2: Tr = acc + R; LN(Tr) -> LNo       (ffn_out+LN)
// MODE 3: Tr = acc + R; no LN               (final ffc_out)
template<int MODE>
__global__ void __launch_bounds__(256) k_gemm64(const unsigned short* __restrict__ Wb,
                                                const unsigned short* __restrict__ Xg,
                                                const float* __restrict__ R,
                                                const float* __restrict__ Base,
                                                const float* __restrict__ gamma,
                                                const float* __restrict__ beta,
                                                float* __restrict__ Tr,
                                                unsigned short* __restrict__ LNo,
                                                int K, int PK){
  __shared__ short SMEM[8704];
  __shared__ float gls[128], bls[128];
  __shared__ float psum[64], pssq[64];
  short* Wls = SMEM;
  short* Xls = SMEM + 5120;
  int b  = blockIdx.z;
  int p0 = blockIdx.x * 64;
  int t  = threadIdx.x;
  int lanelo = t & 15;
  int quad   = (t >> 4) & 3;
  int wv = t >> 6;
  int w2 = wv >> 1, w1 = wv & 1;
  int srw = t >> 1;
  int kow = (t & 1) * 16;
  int srx = t >> 2;
  int kox = (t & 3) * 8;

  if (MODE != 3){
    if (t < 128){ gls[t] = gamma[t]; bls[t] = beta[t]; }
    if (t < 64){ psum[t] = 0.f; pssq[t] = 0.f; }
  }

  float4v acc[4][2];
  #pragma unroll
  for (int i = 0; i < 4; i++){
    acc[i][0] = (float4v){0.f, 0.f, 0.f, 0.f};
    acc[i][1] = (float4v){0.f, 0.f, 0.f, 0.f};
  }
  const unsigned short* Xb = Xg + (size_t)b * cP * PK;

  for (int k0 = 0; k0 < K; k0 += 32){
    short8 xv = *(const short8*)(Xb + (size_t)(p0 + srx) * PK + k0 + kox);
    short8 wv0 = *(const short8*)(Wb + (size_t)srw * K + k0 + kow);
    short8 wv1 = *(const short8*)(Wb + (size_t)srw * K + k0 + kow + 8);
    __syncthreads();
    *(short8*)&Wls[srw * 40 + kow]     = wv0;
    *(short8*)&Wls[srw * 40 + kow + 8] = wv1;
    *(short8*)&Xls[srx * 40 + kox]     = xv;
    __syncthreads();
    short8 af[4], bfr[2];
    #pragma unroll
    for (int i = 0; i < 4; i++)
      af[i] = *(const short8*)&Wls[(w2 * 64 + i * 16 + lanelo) * 40 + quad * 8];
    #pragma unroll
    for (int j = 0; j < 2; j++)
      bfr[j] = *(const short8*)&Xls[(w1 * 32 + j * 16 + lanelo) * 40 + quad * 8];
    #pragma unroll
    for (int i = 0; i < 4; i++)
      #pragma unroll
      for (int j = 0; j < 2; j++)
        acc[i][j] = __builtin_amdgcn_mfma_f32_16x16x32_bf16(af[i], bfr[j], acc[i][j], 0, 0, 0);
  }
  float lnv[4][2][4];
  #pragma unroll
  for (int i = 0; i < 4; i++)
    #pragma unroll
    for (int j = 0; j < 2; j++){
      int n = p0 + w1 * 32 + j * 16 + lanelo;
      #pragma unroll
      for (int r = 0; r < 4; r++){
        int m = w2 * 64 + i * 16 + quad * 4 + r;
        size_t idx = (size_t)b * cC * cP + (size_t)m * cP + n;
        float v = acc[i][j][r];
        if (MODE >= 2) v += R[idx];
        Tr[idx] = v;
        if (MODE == 1) v += Base[idx];
        lnv[i][j][r] = v;
      }
    }
  if (MODE == 3) return;
  __syncthreads();
  #pragma unroll
  for (int j = 0; j < 2; j++){
    int nl = w1 * 32 + j * 16 + lanelo;
    float s = 0.f, ss = 0.f;
    #pragma unroll
    for (int i = 0; i < 4; i++)
      #pragma unroll
      for (int r = 0; r < 4; r++){
        float v = lnv[i][j][r];
        s += v; ss += v * v;
      }
    atomicAdd(&psum[nl], s);
    atomicAdd(&pssq[nl], ss);
  }
  __syncthreads();
  #pragma unroll
  for (int j = 0; j < 2; j++){
    int nl = w1 * 32 + j * 16 + lanelo;
    float mean = psum[nl] * (1.f / cC);
    float var = pssq[nl] * (1.f / cC) - mean * mean;
    float rstd = rsqrtf(var + cEPS);
    #pragma unroll
    for (int i = 0; i < 4; i++)
      #pragma unroll
      for (int r = 0; r < 4; r++){
        int m = w2 * 64 + i * 16 + quad * 4 + r;
        SMEM[nl * 136 + m] = (short)f2b((lnv[i][j][r] - mean) * rstd * gls[m] + bls[m]);
      }
  }
  __syncthreads();
  unsigned short* Ob = LNo + (size_t)b * cP * cC;
  #pragma unroll
  for (int rr = 0; rr < 4; rr++){
    int id = t + rr * 256;
    int row = id >> 4, col8 = (id & 15) * 8;
    short8 sv = *(const short8*)&SMEM[row * 136 + col8];
    *(short8*)(Ob + (size_t)(p0 + row) * cC + col8) = sv;
  }
}

// ---- depthwise 3x3 SAME, [p][c] layout, optional exact gelu ----
template<int GELU, int CCn, int PITCH>
__global__ void __launch_bounds__(256) k_dw(const unsigned short* __restrict__ in,
                                            const float* __restrict__ wt,
                                            unsigned short* __restrict__ out){
  __shared__ float wls[128 * 9];
  int t = threadIdx.x;
  int cbase = blockIdx.y * 128;
  for (int i = t; i < 128 * 9; i += 256){
    int c = cbase + i / 9;
    wls[i] = (c < CCn) ? wt[c * 9 + (i - (i / 9) * 9)] : 0.f;
  }
  __syncthreads();
  int cgl = t & 15, pixl = t >> 4;
  int c0 = cbase + cgl * 8;
  if (c0 >= PITCH) return;
  int p = blockIdx.x * 16 + pixl;
  int h = p >> 7, w = p & 127;
  int b = blockIdx.z;
  float wv[8][9];
  #pragma unroll
  for (int j = 0; j < 8; j++)
    #pragma unroll
    for (int tap = 0; tap < 9; tap++)
      wv[j][tap] = wls[((cgl * 8) + j) * 9 + tap];

  const unsigned short* ib = in + (size_t)b * cP * PITCH;
  float acc[8] = {0,0,0,0,0,0,0,0};
  #pragma unroll
  for (int ky = 0; ky < 3; ky++){
    int hh = h + ky - 1;
    if ((unsigned)hh >= (unsigned)cH) continue;
    #pragma unroll
    for (int kx = 0; kx < 3; kx++){
      int ww = w + kx - 1;
      if ((unsigned)ww >= (unsigned)cW) continue;
      short8 v = *(const short8*)(ib + (size_t)(hh * cW + ww) * PITCH + c0);
      #pragma unroll
      for (int j = 0; j < 8; j++)
        acc[j] += wv[j][ky * 3 + kx] * bfu2f((unsigned short)v[j]);
    }
  }
  short8 ov;
  #pragma unroll
  for (int j = 0; j < 8; j++){
    float v = acc[j];
    if (GELU) v = 0.5f * v * (1.f + erff(v * 0.70710678118654752f));
    ov[j] = (short)f2b(v);
  }
  *(short8*)(out + (size_t)b * cP * PITCH + (size_t)p * PITCH + c0) = ov;
}

// ---- RSA window attention via MFMA ----
__global__ void __launch_bounds__(256) k_rsa(const unsigned short* __restrict__ qkv,
                                             const float* __restrict__ temp,
                                             unsigned short* __restrict__ out){
  constexpr int QT = 0;
  constexpr int KT = 5120;
  constexpr int VO = 10240;
  constexpr int AT = 12416;
  __shared__ short lds[21632];
  __shared__ float nq[16], nk[16];
  int blk = blockIdx.x;
  int b  = blk >> 10;
  int nw = blk & 1023;
  int hb = nw >> 5, wb = nw & 31;
  int t = threadIdx.x;
  #pragma unroll
  for (int j = 0; j < 5; j++)
    *(short8*)&lds[t * 40 + j * 8] = (short8){0,0,0,0,0,0,0,0};
  if (t < 16) nq[t] = 0.f;
  else if (t < 32) nk[t - 16] = 0.f;
  __syncthreads();
  const unsigned short* base = qkv + (size_t)b * cP * cC3;
  #pragma unroll
  for (int r = 0; r < 3; r++){
    int i = t + 256 * r;
    int pix = i / 48;
    int cg = i - pix * 48;
    int c0 = cg * 8;
    int gp = (hb * 4 + (pix >> 2)) * cW + wb * 4 + (pix & 3);
    short8 v = *(const short8*)(base + (size_t)gp * cC3 + c0);
    if (c0 < 256){
      float s = 0.f;
      #pragma unroll
      for (int e = 0; e < 8; e++){ float f = bfu2f((unsigned short)v[e]); s += f * f; }
      int off = (c0 < 128) ? (QT + c0 * 40) : (KT + (c0 - 128) * 40);
      #pragma unroll
      for (int e = 0; e < 8; e++) lds[off + e * 40 + pix] = v[e];
      atomicAdd((c0 < 128) ? &nq[pix] : &nk[pix], s);
    } else {
      *(short8*)&lds[VO + pix * 136 + (c0 - 256)] = v;
    }
  }
  __syncthreads();
  float T = temp[0];
  #pragma unroll
  for (int r = 0; r < 8; r++){
    int idx = t + 256 * r;
    int c = idx >> 4, p = idx & 15;
    float sc = (1.f / fmaxf(sqrtf(nq[p]), 1e-12f)) * (1.f / fmaxf(sqrtf(nk[p]), 1e-12f));
    int a = QT + c * 40 + p;
    lds[a] = (short)f2b(bfu2f((unsigned short)lds[a]) * sc);
  }
  __syncthreads();
  int lanelo = t & 15;
  int quad = (t >> 4) & 3;
  int wv = t >> 6;
  float4v oacc[2];
  oacc[0] = (float4v){0.f,0.f,0.f,0.f};
  oacc[1] = (float4v){0.f,0.f,0.f,0.f};
  for (int ch = 0; ch < 2; ch++){
    #pragma unroll
    for (int ct = 0; ct < 4; ct++){
      int c0 = ch * 64 + ct * 16;
      short8 af = *(const short8*)&lds[QT + (c0 + lanelo) * 40 + quad * 8];
      #pragma unroll
      for (int dt = 0; dt < 2; dt++){
        int d0 = wv * 32 + dt * 16;
        short8 bf = *(const short8*)&lds[KT + (d0 + lanelo) * 40 + quad * 8];
        float4v acc = __builtin_amdgcn_mfma_f32_16x16x32_bf16(af, bf,
                        (float4v){0.f,0.f,0.f,0.f}, 0, 0, 0);
        short4v sv;
        #pragma unroll
        for (int r2 = 0; r2 < 4; r2++) sv[r2] = (short)f2b(fmaxf(acc[r2] * T, 0.f));
        *(short4v*)&lds[AT + (d0 + lanelo) * 72 + ct * 16 + quad * 4] = sv;
      }
    }
    __syncthreads();
    #pragma unroll
    for (int dt = 0; dt < 2; dt++){
      int d0 = wv * 32 + dt * 16;
      #pragma unroll
      for (int kk = 0; kk < 2; kk++){
        short8 av8 = *(const short8*)&lds[VO + lanelo * 136 + ch * 64 + kk * 32 + quad * 8];
        short8 bv8 = *(const short8*)&lds[AT + (d0 + lanelo) * 72 + kk * 32 + quad * 8];
        oacc[dt] = __builtin_amdgcn_mfma_f32_16x16x32_bf16(av8, bv8, oacc[dt], 0, 0, 0);
      }
    }
    __syncthreads();
  }
  #pragma unroll
  for (int dt = 0; dt < 2; dt++){
    int d = wv * 32 + dt * 16 + lanelo;
    #pragma unroll
    for (int r2 = 0; r2 < 4; r2++){
      int p = quad * 4 + r2;
      int h2 = (hb * 4 + (p >> 2) + 2) & (cH - 1);
      int w2 = (wb * 4 + (p & 3) + 2) & (cW - 1);
      out[(size_t)b * cP * cC + (size_t)(h2 * cW + w2) * cC + d] = f2b(oacc[dt][r2]);
    }
  }
}

// ---- GSA Gram ----
__global__ void __launch_bounds__(256) k_gram(const unsigned short* __restrict__ qkv,
                                              float* __restrict__ S,
                                              float* __restrict__ Qn,
                                              float* __restrict__ Kn){
  __shared__ float qs[32][132];
  __shared__ float ks[32][132];
  int blk = blockIdx.x;
  int chunk = blk & 127;
  int bh = blk >> 7;
  int b = bh >> 2, hd = bh & 3;
  int n0 = chunk * 128;
  int t = threadIdx.x;
  {
    int row = t >> 1;
    int half = t & 1;
    const unsigned short* pq = qkv + (size_t)b * cP * cC3 + (size_t)(n0 + row) * cC3 + hd * 32 + half * 16;
    const unsigned short* pk = pq + 128;
    short8 q0 = *(const short8*)pq;
    short8 q1 = *(const short8*)(pq + 8);
    short8 k0 = *(const short8*)pk;
    short8 k1 = *(const short8*)(pk + 8);
    #pragma unroll
    for (int e = 0; e < 8; e++){
      qs[half * 16 + e][row]     = bfu2f((unsigned short)q0[e]);
      qs[half * 16 + 8 + e][row] = bfu2f((unsigned short)q1[e]);
      ks[half * 16 + e][row]     = bfu2f((unsigned short)k0[e]);
      ks[half * 16 + 8 + e][row] = bfu2f((unsigned short)k1[e]);
    }
  }
  __syncthreads();
  if (t < 64){
    const float* row = (t < 32) ? qs[t] : ks[t - 32];
    float s = 0.f;
    #pragma unroll
    for (int i = 0; i < 128; i += 4){
      float4 v = *(const float4*)(row + i);
      s += v.x*v.x + v.y*v.y + v.z*v.z + v.w*v.w;
    }
    if (t < 32) atomicAdd(&Qn[bh * 32 + t], s);
    else        atomicAdd(&Kn[bh * 32 + (t - 32)], s);
  }
  int cc = (t >> 4) * 2;
  int dd = t & 15;
  float a00 = 0.f, a01 = 0.f, a10 = 0.f, a11 = 0.f;
  for (int n = 0; n < 128; n += 4){
    float4 q0 = *(const float4*)&qs[cc][n];
    float4 q1 = *(const float4*)&qs[cc + 1][n];
    float4 k0 = *(const float4*)&ks[dd][n];
    float4 k1 = *(const float4*)&ks[dd + 16][n];
    a00 += q0.x*k0.x + q0.y*k0.y + q0.z*k0.z + q0.w*k0.w;
    a01 += q0.x*k1.x + q0.y*k1.y + q0.z*k1.z + q0.w*k1.w;
    a10 += q1.x*k0.x + q1.y*k0.y + q1.z*k0.z + q1.w*k0.w;
    a11 += q1.x*k1.x + q1.y*k1.y + q1.z*k1.z + q1.w*k1.w;
  }
  float* Sb = S + (size_t)bh * 1024;
  atomicAdd(&Sb[cc * 32 + dd], a00);
  atomicAdd(&Sb[cc * 32 + dd + 16], a01);
  atomicAdd(&Sb[(cc + 1) * 32 + dd], a10);
  atomicAdd(&Sb[(cc + 1) * 32 + dd + 16], a11);
}

// ---- GSA apply with inlined finalize ----
__global__ void __launch_bounds__(256) k_apply(const unsigned short* __restrict__ qkv,
                                               const float* __restrict__ S,
                                               const float* __restrict__ Qn,
                                               const float* __restrict__ Kn,
                                               const float* __restrict__ temp,
                                               unsigned short* __restrict__ out){
  __shared__ float at[1024];
  int blk = blockIdx.x;
  int tile = blk & 63;
  int bh = blk >> 6;
  int b = bh >> 2, hd = bh & 3;
  int t = threadIdx.x;
  float T = temp[0];
  for (int i = t; i < 1024; i += 256){
    int c = i >> 5, d = i & 31;
    float nqv = fmaxf(sqrtf(Qn[bh * 32 + c]), 1e-12f);
    float nkv = fmaxf(sqrtf(Kn[bh * 32 + d]), 1e-12f);
    at[i] = fmaxf(S[bh * 1024 + i] / (nqv * nkv) * T, 0.f);
  }
  __syncthreads();
  int n = tile * 256 + t;
  const unsigned short* vb = qkv + (size_t)b * cP * cC3 + (size_t)n * cC3 + 256 + hd * 32;
  float vr[32];
  #pragma unroll
  for (int d8 = 0; d8 < 32; d8 += 8){
    short8 v = *(const short8*)(vb + d8);
    #pragma unroll
    for (int e = 0; e < 8; e++) vr[d8 + e] = bfu2f((unsigned short)v[e]);
  }
  unsigned short* ob = out + (size_t)b * cP * cC + (size_t)n * cC + hd * 32;
  #pragma unroll
  for (int c8 = 0; c8 < 32; c8 += 8){
    short8 ov;
    #pragma unroll
    for (int e = 0; e < 8; e++){
      const float* ar = &at[(c8 + e) * 32];
      float acc = 0.f;
      #pragma unroll
      for (int d = 0; d < 32; d += 4){
        float4 a4 = *(const float4*)(ar + d);
        acc += a4.x * vr[d] + a4.y * vr[d+1] + a4.z * vr[d+2] + a4.w * vr[d+3];
      }
      ov[e] = (short)f2b(acc);
    }
    *(short8*)(ob + c8) = ov;
  }
}

extern "C" void kernel_launch(void* const* d_in, const int* in_sizes, int n_in,
                              void* d_out, int out_size, void* d_ws, size_t ws_size,
                              hipStream_t stream){
  const float* x     = (const float*)d_in[0];
  const float* w_s0  = (const float*)d_in[1];
  const float* b_s0  = (const float*)d_in[2];
  const float* w_s2  = (const float*)d_in[3];
  const float* b_s2  = (const float*)d_in[4];
  const float* rsa_qkv  = (const float*)d_in[5];
  const float* rsa_dw   = (const float*)d_in[6];
  const float* rsa_proj = (const float*)d_in[7];
  const float* rsa_temp = (const float*)d_in[8];
  const float* ffs_in   = (const float*)d_in[9];
  const float* ffs_dw   = (const float*)d_in[10];
  const float* ffs_out  = (const float*)d_in[11];
  const float* w_c0  = (const float*)d_in[12];
  const float* b_c0  = (const float*)d_in[13];
  const float* w_c2  = (const float*)d_in[14];
  const float* b_c2  = (const float*)d_in[15];
  const float* gsa_qkv  = (const float*)d_in[16];
  const float* gsa_dw   = (const float*)d_in[17];
  const float* gsa_proj = (const float*)d_in[18];
  const float* gsa_temp = (const float*)d_in[19];
  const float* ffc_in   = (const float*)d_in[20];
  const float* ffc_dw   = (const float*)d_in[21];
  const float* ffc_out  = (const float*)d_in[22];

  const size_t szC  = (size_t)cB * cC * cP;
  const size_t szC3 = (size_t)cB * cC3 * cP;
  float* XF = (float*)d_ws;                       // x2 fp32 [c][p]
  float* XS = XF + szC;                           // x_ fp32 [c][p]
  unsigned short* LO   = (unsigned short*)(XS + szC);
  unsigned short* Abuf = LO + szC;
  unsigned short* Bbuf = Abuf + szC3;
  float* S  = (float*)(Bbuf + szC3);
  float* Qn = S + 8192;
  float* Kn = Qn + 256;
  float* AT = Kn + 256;
  unsigned short* WB = (unsigned short*)(AT + 1024);
  unsigned short* W_QKV_S = WB;
  unsigned short* W_QKV_C = WB + 49152;
  unsigned short* W_FIN_S = WB + 98304;
  unsigned short* W_FIN_C = WB + 147456;
  unsigned short* W_PRJ_S = WB + 196608;
  unsigned short* W_PRJ_C = WB + 212992;
  unsigned short* W_FO_S  = WB + 229376;
  unsigned short* W_FO_C  = WB + 274432;

  dim3 t256(256);
  dim3 gLN(cB * cP / 256);
  dim3 gG(cP / 64, 1, cB);     // new k_gemm grid: 64px blocks, m-loop inside
  dim3 gG64(cP / 64, 1, cB);
  dim3 gDW(cP / 16, 3, cB);

  k_wcvt<<<dim3(1282), t256, 0, stream>>>(rsa_qkv, gsa_qkv, ffs_in, ffc_in,
                                          rsa_proj, gsa_proj, ffs_out, ffc_out, WB, S);

  // ---------------- spatial (RSA) block ----------------
  k_ln<<<gLN, t256, 0, stream>>>(x, w_s0, b_s0, LO, 126, 126);
  k_gemm<<<gG, t256, 0, stream>>>(W_QKV_S, LO, Abuf, 384);
  k_dw<0,384,384><<<gDW, t256, 0, stream>>>(Abuf, rsa_dw, Bbuf);
  k_rsa<<<dim3(cB * cNW), t256, 0, stream>>>(Bbuf, rsa_temp, LO);
  k_gemm64<1><<<gG64, t256, 0, stream>>>(W_PRJ_S, LO, nullptr, x, w_s2, b_s2, XS, LO, 128, 128);
  k_gemm<<<gG, t256, 0, stream>>>(W_FIN_S, LO, Abuf, 352);
  k_dw<1,340,352><<<gDW, t256, 0, stream>>>(Abuf, ffs_dw, Bbuf);
  k_gemm64<2><<<gG64, t256, 0, stream>>>(W_FO_S, Bbuf, XS, nullptr, w_c0, b_c0, XF, LO, 352, 352);

  // ---------------- channel (GSA) block ----------------
  k_gemm<<<gG, t256, 0, stream>>>(W_QKV_C, LO, Abuf, 384);
  k_dw<0,384,384><<<gDW, t256, 0, stream>>>(Abuf, gsa_dw, Bbuf);
  k_gram<<<dim3(1024), t256, 0, stream>>>(Bbuf, S, Qn, Kn);
  k_apply<<<dim3(512), t256, 0, stream>>>(Bbuf, S, Qn, Kn, gsa_temp, LO);
  k_gemm64<1><<<gG64, t256, 0, stream>>>(W_PRJ_C, LO, nullptr, XF, w_c2, b_c2, XS, LO, 128, 128);
  k_gemm<<<gG, t256, 0, stream>>>(W_FIN_C, LO, Abuf, 352);
  k_dw<1,340,352><<<gDW, t256, 0, stream>>>(Abuf, ffc_dw, Bbuf);
  k_gemm64<3><<<gG64, t256, 0, stream>>>(W_FO_C, Bbuf, XS, nullptr, nullptr, nullptr,
                                         (float*)d_out, nullptr, 352, 352);
}

// Round 13
// 362.206 us; speedup vs baseline: 1.1921x; 1.1921x over previous
//
#include <hip/hip_runtime.h>
#include <hip/hip_bf16.h>
#include <math.h>

typedef __hip_bfloat16 bf16;
typedef __attribute__((ext_vector_type(8))) short short8;
typedef __attribute__((ext_vector_type(4))) short short4v;
typedef __attribute__((ext_vector_type(4))) float float4v;

static constexpr int cB  = 2;
static constexpr int cC  = 128;
static constexpr int cH  = 128;
static constexpr int cW  = 128;
static constexpr int cP  = cH * cW;       // 16384
static constexpr int cC3 = 384;
static constexpr int cHID = 340;
static constexpr int cNW = 1024;
static constexpr float cEPS = 1e-6f;

__device__ __forceinline__ float bfu2f(unsigned short u){
  union { unsigned int i; float f; } c; c.i = ((unsigned int)u) << 16; return c.f;
}
__device__ __forceinline__ unsigned short f2b(float f){
  union { float f; unsigned int u; } c; c.f = f;
  unsigned int r = c.u + 0x7FFFu + ((c.u >> 16) & 1u);
  return (unsigned short)(r >> 16);
}

// ---- convert all 8 weight matrices fp32 -> bf16 (with padding) into WB; tail zeroes S
__global__ void k_wcvt(const float* __restrict__ qkv_s, const float* __restrict__ qkv_c,
                       const float* __restrict__ fin_s, const float* __restrict__ fin_c,
                       const float* __restrict__ prj_s, const float* __restrict__ prj_c,
                       const float* __restrict__ fo_s,  const float* __restrict__ fo_c,
                       unsigned short* __restrict__ WB, float* __restrict__ S){
  int i = blockIdx.x * 256 + threadIdx.x;
  if (i >= 319488){
    int j = i - 319488;
    if (j < 8704) S[j] = 0.f;
    return;
  }
  float v;
  if (i < 98304){
    v = (i < 49152) ? qkv_s[i] : qkv_c[i - 49152];
  } else if (i < 196608){
    int j = (i < 147456) ? (i - 98304) : (i - 147456);
    int row = j >> 7, col = j & 127;
    const float* src = (i < 147456) ? fin_s : fin_c;
    v = (row < cHID) ? src[row * 128 + col] : 0.f;
  } else if (i < 229376){
    v = (i < 212992) ? prj_s[i - 196608] : prj_c[i - 212992];
  } else {
    int j = (i < 274432) ? (i - 229376) : (i - 274432);
    int row = j / 352, col = j - row * 352;
    const float* src = (i < 274432) ? fo_s : fo_c;
    v = (col < cHID) ? src[row * cHID + col] : 0.f;
  }
  WB[i] = f2b(v);
}

// ---- standalone LayerNorm (first LN only): fp32 [c][p] -> bf16 [p][128], roll shift
__global__ void __launch_bounds__(256) k_ln(const float* __restrict__ a,
                                            const float* __restrict__ gamma,
                                            const float* __restrict__ beta,
                                            unsigned short* __restrict__ out, int sh, int sw){
  int idx = blockIdx.x * 256 + threadIdx.x;
  if (idx >= cB * cP) return;
  int b = idx >> 14;
  int p = idx & (cP - 1);
  const float* ap = a + (size_t)b * cC * cP + p;
  float s = 0.f, ss = 0.f;
  #pragma unroll 8
  for (int c = 0; c < cC; c++){
    float v = ap[c * cP];
    s += v; ss += v * v;
  }
  float m = s * (1.f / cC);
  float var = ss * (1.f / cC) - m * m;
  float rstd = rsqrtf(var + cEPS);
  int h = p >> 7, w = p & 127;
  int h2 = (h + sh) & (cH - 1);
  int w2 = (w + sw) & (cW - 1);
  unsigned short* op = out + (size_t)b * cP * cC + (size_t)(h2 * cW + w2) * cC;
  #pragma unroll
  for (int c8 = 0; c8 < cC; c8 += 8){
    short8 tv;
    #pragma unroll
    for (int j = 0; j < 8; j++){
      float v = ap[(c8 + j) * cP];
      tv[j] = (short)f2b((v - m) * rstd * gamma[c8 + j] + beta[c8 + j]);
    }
    *(short8*)(op + c8) = tv;
  }
}

// ---- MFMA GEMM (round-11 structure): 128px x 128m tile, K-loop, bf16 out [p][m] ----
__global__ void __launch_bounds__(256) k_gemm(const unsigned short* __restrict__ Wb,
                                              const unsigned short* __restrict__ Xg,
                                              unsigned short* __restrict__ Out,
                                              int K, int PK, int PM){
  __shared__ short Wls[128 * 40];
  __shared__ short Xls[128 * 40];
  int b  = blockIdx.z;
  int p0 = blockIdx.x * 128;
  int m0 = blockIdx.y * 128;
  int t  = threadIdx.x;
  int lanelo = t & 15;
  int quad   = (t >> 4) & 3;
  int wv = t >> 6;
  int w2 = wv >> 1, w1 = wv & 1;
  int srow = t >> 1;
  int koff = (t & 1) * 16;

  float4v acc[4][4];
  #pragma unroll
  for (int i = 0; i < 4; i++)
    #pragma unroll
    for (int j = 0; j < 4; j++)
      acc[i][j] = (float4v){0.f, 0.f, 0.f, 0.f};

  const unsigned short* Xb = Xg + (size_t)b * cP * PK;

  for (int k0 = 0; k0 < K; k0 += 32){
    short8 xv0 = *(const short8*)(Xb + (size_t)(p0 + srow) * PK + k0 + koff);
    short8 xv1 = *(const short8*)(Xb + (size_t)(p0 + srow) * PK + k0 + koff + 8);
    short8 wv0 = *(const short8*)(Wb + (size_t)(m0 + srow) * K + k0 + koff);
    short8 wv1 = *(const short8*)(Wb + (size_t)(m0 + srow) * K + k0 + koff + 8);
    __syncthreads();
    *(short8*)&Wls[srow * 40 + koff]     = wv0;
    *(short8*)&Wls[srow * 40 + koff + 8] = wv1;
    *(short8*)&Xls[srow * 40 + koff]     = xv0;
    *(short8*)&Xls[srow * 40 + koff + 8] = xv1;
    __syncthreads();
    short8 af[4], bfr[4];
    #pragma unroll
    for (int i = 0; i < 4; i++)
      af[i] = *(const short8*)&Xls[(w2 * 64 + i * 16 + lanelo) * 40 + quad * 8];
    #pragma unroll
    for (int j = 0; j < 4; j++)
      bfr[j] = *(const short8*)&Wls[(w1 * 64 + j * 16 + lanelo) * 40 + quad * 8];
    #pragma unroll
    for (int i = 0; i < 4; i++)
      #pragma unroll
      for (int j = 0; j < 4; j++)
        acc[i][j] = __builtin_amdgcn_mfma_f32_16x16x32_bf16(af[i], bfr[j], acc[i][j], 0, 0, 0);
  }
  unsigned short* Ob = Out + (size_t)b * cP * PM;
  #pragma unroll
  for (int i = 0; i < 4; i++)
    #pragma unroll
    for (int j = 0; j < 4; j++){
      int wrow = m0 + w1 * 64 + j * 16 + lanelo;
      if (wrow >= PM) continue;
      #pragma unroll
      for (int r = 0; r < 4; r++){
        int pix = p0 + w2 * 64 + i * 16 + quad * 4 + r;
        Ob[(size_t)pix * PM + wrow] = f2b(acc[i][j][r]);
      }
    }
}

// ---- MFMA GEMM 64px x 128m (M=128) with fused epilogue.
// MODE 1: Tr = acc; LN(Base + acc) -> LNo   (proj+LN)
// MODE 2: Tr = acc + R; LN(Tr) -> LNo       (ffn_out+LN)
// MODE 3: Tr = acc + R; no LN               (final ffc_out)
template<int MODE>
__global__ void __launch_bounds__(256) k_gemm64(const unsigned short* __restrict__ Wb,
                                                const unsigned short* __restrict__ Xg,
                                                const float* __restrict__ R,
                                                const float* __restrict__ Base,
                                                const float* __restrict__ gamma,
                                                const float* __restrict__ beta,
                                                float* __restrict__ Tr,
                                                unsigned short* __restrict__ LNo,
                                                int K, int PK){
  __shared__ short SMEM[8704];
  __shared__ float gls[128], bls[128];
  __shared__ float psum[64], pssq[64];
  short* Wls = SMEM;
  short* Xls = SMEM + 5120;
  int b  = blockIdx.z;
  int p0 = blockIdx.x * 64;
  int t  = threadIdx.x;
  int lanelo = t & 15;
  int quad   = (t >> 4) & 3;
  int wv = t >> 6;
  int w2 = wv >> 1, w1 = wv & 1;
  int srw = t >> 1;
  int kow = (t & 1) * 16;
  int srx = t >> 2;
  int kox = (t & 3) * 8;

  if (MODE != 3){
    if (t < 128){ gls[t] = gamma[t]; bls[t] = beta[t]; }
    if (t < 64){ psum[t] = 0.f; pssq[t] = 0.f; }
  }

  float4v acc[4][2];
  #pragma unroll
  for (int i = 0; i < 4; i++){
    acc[i][0] = (float4v){0.f, 0.f, 0.f, 0.f};
    acc[i][1] = (float4v){0.f, 0.f, 0.f, 0.f};
  }
  const unsigned short* Xb = Xg + (size_t)b * cP * PK;

  for (int k0 = 0; k0 < K; k0 += 32){
    short8 xv = *(const short8*)(Xb + (size_t)(p0 + srx) * PK + k0 + kox);
    short8 wv0 = *(const short8*)(Wb + (size_t)srw * K + k0 + kow);
    short8 wv1 = *(const short8*)(Wb + (size_t)srw * K + k0 + kow + 8);
    __syncthreads();
    *(short8*)&Wls[srw * 40 + kow]     = wv0;
    *(short8*)&Wls[srw * 40 + kow + 8] = wv1;
    *(short8*)&Xls[srx * 40 + kox]     = xv;
    __syncthreads();
    short8 af[4], bfr[2];
    #pragma unroll
    for (int i = 0; i < 4; i++)
      af[i] = *(const short8*)&Wls[(w2 * 64 + i * 16 + lanelo) * 40 + quad * 8];
    #pragma unroll
    for (int j = 0; j < 2; j++)
      bfr[j] = *(const short8*)&Xls[(w1 * 32 + j * 16 + lanelo) * 40 + quad * 8];
    #pragma unroll
    for (int i = 0; i < 4; i++)
      #pragma unroll
      for (int j = 0; j < 2; j++)
        acc[i][j] = __builtin_amdgcn_mfma_f32_16x16x32_bf16(af[i], bfr[j], acc[i][j], 0, 0, 0);
  }
  float lnv[4][2][4];
  #pragma unroll
  for (int i = 0; i < 4; i++)
    #pragma unroll
    for (int j = 0; j < 2; j++){
      int n = p0 + w1 * 32 + j * 16 + lanelo;
      #pragma unroll
      for (int r = 0; r < 4; r++){
        int m = w2 * 64 + i * 16 + quad * 4 + r;
        size_t idx = (size_t)b * cC * cP + (size_t)m * cP + n;
        float v = acc[i][j][r];
        if (MODE >= 2) v += R[idx];
        Tr[idx] = v;
        if (MODE == 1) v += Base[idx];
        lnv[i][j][r] = v;
      }
    }
  if (MODE == 3) return;
  __syncthreads();
  #pragma unroll
  for (int j = 0; j < 2; j++){
    int nl = w1 * 32 + j * 16 + lanelo;
    float s = 0.f, ss = 0.f;
    #pragma unroll
    for (int i = 0; i < 4; i++)
      #pragma unroll
      for (int r = 0; r < 4; r++){
        float v = lnv[i][j][r];
        s += v; ss += v * v;
      }
    atomicAdd(&psum[nl], s);
    atomicAdd(&pssq[nl], ss);
  }
  __syncthreads();
  #pragma unroll
  for (int j = 0; j < 2; j++){
    int nl = w1 * 32 + j * 16 + lanelo;
    float mean = psum[nl] * (1.f / cC);
    float var = pssq[nl] * (1.f / cC) - mean * mean;
    float rstd = rsqrtf(var + cEPS);
    #pragma unroll
    for (int i = 0; i < 4; i++)
      #pragma unroll
      for (int r = 0; r < 4; r++){
        int m = w2 * 64 + i * 16 + quad * 4 + r;
        SMEM[nl * 136 + m] = (short)f2b((lnv[i][j][r] - mean) * rstd * gls[m] + bls[m]);
      }
  }
  __syncthreads();
  unsigned short* Ob = LNo + (size_t)b * cP * cC;
  #pragma unroll
  for (int rr = 0; rr < 4; rr++){
    int id = t + rr * 256;
    int row = id >> 4, col8 = (id & 15) * 8;
    short8 sv = *(const short8*)&SMEM[row * 136 + col8];
    *(short8*)(Ob + (size_t)(p0 + row) * cC + col8) = sv;
  }
}

// ---- depthwise 3x3 SAME, [p][c] layout, optional exact gelu.
// Weights LDS stride 76 ([cg][tap*8+j]) -> 2-way-free reads, cached in regs as float4.
// Unconditional clamped loads (no branches), OOB zeroed by cndmask.
template<int GELU, int CCn, int PITCH>
__global__ void __launch_bounds__(256) k_dw(const unsigned short* __restrict__ in,
                                            const float* __restrict__ wt,
                                            unsigned short* __restrict__ out){
  __shared__ float wls[16 * 76];
  int t = threadIdx.x;
  int cbase = blockIdx.y * 128;
  for (int i = t; i < 16 * 72; i += 256){
    int cg = i / 72, rem = i - cg * 72;     // rem = tap*8 + j
    int tap = rem >> 3, j = rem & 7;
    int c = cbase + cg * 8 + j;
    wls[cg * 76 + rem] = (c < CCn) ? wt[c * 9 + tap] : 0.f;
  }
  __syncthreads();
  int cgl = t & 15, pixl = t >> 4;
  int c0 = cbase + cgl * 8;
  if (c0 >= PITCH) return;
  int p = blockIdx.x * 16 + pixl;
  int h = p >> 7, w = p & 127;
  int b = blockIdx.z;
  const unsigned short* ib = in + (size_t)b * cP * PITCH;
  // weights into registers: 18 float4 = [tap][j-half]
  float4 wreg[18];
  #pragma unroll
  for (int q = 0; q < 18; q++)
    wreg[q] = *(const float4*)&wls[cgl * 76 + q * 4];
  // 9 unconditional loads with clamped addresses
  short8 v[9];
  #pragma unroll
  for (int ky = 0; ky < 3; ky++){
    int hh = h + ky - 1;
    bool okh = (unsigned)hh < (unsigned)cH;
    int hc = okh ? hh : h;
    #pragma unroll
    for (int kx = 0; kx < 3; kx++){
      int ww = w + kx - 1;
      bool okw = (unsigned)ww < (unsigned)cW;
      int wc = okw ? ww : w;
      short8 lv = *(const short8*)(ib + (size_t)(hc * cW + wc) * PITCH + c0);
      if (!(okh && okw)) lv = (short8){0,0,0,0,0,0,0,0};
      v[ky * 3 + kx] = lv;
    }
  }
  float acc[8] = {0,0,0,0,0,0,0,0};
  #pragma unroll
  for (int tap = 0; tap < 9; tap++){
    float4 w0 = wreg[tap * 2];
    float4 w1 = wreg[tap * 2 + 1];
    float wa[8] = {w0.x, w0.y, w0.z, w0.w, w1.x, w1.y, w1.z, w1.w};
    #pragma unroll
    for (int j = 0; j < 8; j++)
      acc[j] += wa[j] * bfu2f((unsigned short)v[tap][j]);
  }
  short8 ov;
  #pragma unroll
  for (int j = 0; j < 8; j++){
    float vv = acc[j];
    if (GELU) vv = 0.5f * vv * (1.f + erff(vv * 0.70710678118654752f));
    ov[j] = (short)f2b(vv);
  }
  *(short8*)(out + (size_t)b * cP * PITCH + (size_t)p * PITCH + c0) = ov;
}

// ---- RSA window attention via MFMA ----
__global__ void __launch_bounds__(256) k_rsa(const unsigned short* __restrict__ qkv,
                                             const float* __restrict__ temp,
                                             unsigned short* __restrict__ out){
  constexpr int QT = 0;
  constexpr int KT = 5120;
  constexpr int VO = 10240;
  constexpr int AT = 12416;
  __shared__ short lds[21632];
  __shared__ float nq[16], nk[16];
  int blk = blockIdx.x;
  int b  = blk >> 10;
  int nw = blk & 1023;
  int hb = nw >> 5, wb = nw & 31;
  int t = threadIdx.x;
  #pragma unroll
  for (int j = 0; j < 5; j++)
    *(short8*)&lds[t * 40 + j * 8] = (short8){0,0,0,0,0,0,0,0};
  if (t < 16) nq[t] = 0.f;
  else if (t < 32) nk[t - 16] = 0.f;
  __syncthreads();
  const unsigned short* base = qkv + (size_t)b * cP * cC3;
  #pragma unroll
  for (int r = 0; r < 3; r++){
    int i = t + 256 * r;
    int pix = i / 48;
    int cg = i - pix * 48;
    int c0 = cg * 8;
    int gp = (hb * 4 + (pix >> 2)) * cW + wb * 4 + (pix & 3);
    short8 v = *(const short8*)(base + (size_t)gp * cC3 + c0);
    if (c0 < 256){
      float s = 0.f;
      #pragma unroll
      for (int e = 0; e < 8; e++){ float f = bfu2f((unsigned short)v[e]); s += f * f; }
      int off = (c0 < 128) ? (QT + c0 * 40) : (KT + (c0 - 128) * 40);
      #pragma unroll
      for (int e = 0; e < 8; e++) lds[off + e * 40 + pix] = v[e];
      atomicAdd((c0 < 128) ? &nq[pix] : &nk[pix], s);
    } else {
      *(short8*)&lds[VO + pix * 136 + (c0 - 256)] = v;
    }
  }
  __syncthreads();
  float T = temp[0];
  #pragma unroll
  for (int r = 0; r < 8; r++){
    int idx = t + 256 * r;
    int c = idx >> 4, p = idx & 15;
    float sc = (1.f / fmaxf(sqrtf(nq[p]), 1e-12f)) * (1.f / fmaxf(sqrtf(nk[p]), 1e-12f));
    int a = QT + c * 40 + p;
    lds[a] = (short)f2b(bfu2f((unsigned short)lds[a]) * sc);
  }
  __syncthreads();
  int lanelo = t & 15;
  int quad = (t >> 4) & 3;
  int wv = t >> 6;
  float4v oacc[2];
  oacc[0] = (float4v){0.f,0.f,0.f,0.f};
  oacc[1] = (float4v){0.f,0.f,0.f,0.f};
  for (int ch = 0; ch < 2; ch++){
    #pragma unroll
    for (int ct = 0; ct < 4; ct++){
      int c0 = ch * 64 + ct * 16;
      short8 af = *(const short8*)&lds[QT + (c0 + lanelo) * 40 + quad * 8];
      #pragma unroll
      for (int dt = 0; dt < 2; dt++){
        int d0 = wv * 32 + dt * 16;
        short8 bf = *(const short8*)&lds[KT + (d0 + lanelo) * 40 + quad * 8];
        float4v acc = __builtin_amdgcn_mfma_f32_16x16x32_bf16(af, bf,
                        (float4v){0.f,0.f,0.f,0.f}, 0, 0, 0);
        short4v sv;
        #pragma unroll
        for (int r2 = 0; r2 < 4; r2++) sv[r2] = (short)f2b(fmaxf(acc[r2] * T, 0.f));
        *(short4v*)&lds[AT + (d0 + lanelo) * 72 + ct * 16 + quad * 4] = sv;
      }
    }
    __syncthreads();
    #pragma unroll
    for (int dt = 0; dt < 2; dt++){
      int d0 = wv * 32 + dt * 16;
      #pragma unroll
      for (int kk = 0; kk < 2; kk++){
        short8 av8 = *(const short8*)&lds[VO + lanelo * 136 + ch * 64 + kk * 32 + quad * 8];
        short8 bv8 = *(const short8*)&lds[AT + (d0 + lanelo) * 72 + kk * 32 + quad * 8];
        oacc[dt] = __builtin_amdgcn_mfma_f32_16x16x32_bf16(av8, bv8, oacc[dt], 0, 0, 0);
      }
    }
    __syncthreads();
  }
  #pragma unroll
  for (int dt = 0; dt < 2; dt++){
    int d = wv * 32 + dt * 16 + lanelo;
    #pragma unroll
    for (int r2 = 0; r2 < 4; r2++){
      int p = quad * 4 + r2;
      int h2 = (hb * 4 + (p >> 2) + 2) & (cH - 1);
      int w2 = (wb * 4 + (p & 3) + 2) & (cW - 1);
      out[(size_t)b * cP * cC + (size_t)(h2 * cW + w2) * cC + d] = f2b(oacc[dt][r2]);
    }
  }
}

// ---- GSA Gram ----
__global__ void __launch_bounds__(256) k_gram(const unsigned short* __restrict__ qkv,
                                              float* __restrict__ S,
                                              float* __restrict__ Qn,
                                              float* __restrict__ Kn){
  __shared__ float qs[32][132];
  __shared__ float ks[32][132];
  int blk = blockIdx.x;
  int chunk = blk & 127;
  int bh = blk >> 7;
  int b = bh >> 2, hd = bh & 3;
  int n0 = chunk * 128;
  int t = threadIdx.x;
  {
    int row = t >> 1;
    int half = t & 1;
    const unsigned short* pq = qkv + (size_t)b * cP * cC3 + (size_t)(n0 + row) * cC3 + hd * 32 + half * 16;
    const unsigned short* pk = pq + 128;
    short8 q0 = *(const short8*)pq;
    short8 q1 = *(const short8*)(pq + 8);
    short8 k0 = *(const short8*)pk;
    short8 k1 = *(const short8*)(pk + 8);
    #pragma unroll
    for (int e = 0; e < 8; e++){
      qs[half * 16 + e][row]     = bfu2f((unsigned short)q0[e]);
      qs[half * 16 + 8 + e][row] = bfu2f((unsigned short)q1[e]);
      ks[half * 16 + e][row]     = bfu2f((unsigned short)k0[e]);
      ks[half * 16 + 8 + e][row] = bfu2f((unsigned short)k1[e]);
    }
  }
  __syncthreads();
  if (t < 64){
    const float* row = (t < 32) ? qs[t] : ks[t - 32];
    float s = 0.f;
    #pragma unroll
    for (int i = 0; i < 128; i += 4){
      float4 v = *(const float4*)(row + i);
      s += v.x*v.x + v.y*v.y + v.z*v.z + v.w*v.w;
    }
    if (t < 32) atomicAdd(&Qn[bh * 32 + t], s);
    else        atomicAdd(&Kn[bh * 32 + (t - 32)], s);
  }
  int cc = (t >> 4) * 2;
  int dd = t & 15;
  float a00 = 0.f, a01 = 0.f, a10 = 0.f, a11 = 0.f;
  for (int n = 0; n < 128; n += 4){
    float4 q0 = *(const float4*)&qs[cc][n];
    float4 q1 = *(const float4*)&qs[cc + 1][n];
    float4 k0 = *(const float4*)&ks[dd][n];
    float4 k1 = *(const float4*)&ks[dd + 16][n];
    a00 += q0.x*k0.x + q0.y*k0.y + q0.z*k0.z + q0.w*k0.w;
    a01 += q0.x*k1.x + q0.y*k1.y + q0.z*k1.z + q0.w*k1.w;
    a10 += q1.x*k0.x + q1.y*k0.y + q1.z*k0.z + q1.w*k0.w;
    a11 += q1.x*k1.x + q1.y*k1.y + q1.z*k1.z + q1.w*k1.w;
  }
  float* Sb = S + (size_t)bh * 1024;
  atomicAdd(&Sb[cc * 32 + dd], a00);
  atomicAdd(&Sb[cc * 32 + dd + 16], a01);
  atomicAdd(&Sb[(cc + 1) * 32 + dd], a10);
  atomicAdd(&Sb[(cc + 1) * 32 + dd + 16], a11);
}

// ---- GSA apply with inlined finalize ----
__global__ void __launch_bounds__(256) k_apply(const unsigned short* __restrict__ qkv,
                                               const float* __restrict__ S,
                                               const float* __restrict__ Qn,
                                               const float* __restrict__ Kn,
                                               const float* __restrict__ temp,
                                               unsigned short* __restrict__ out){
  __shared__ float at[1024];
  int blk = blockIdx.x;
  int tile = blk & 63;
  int bh = blk >> 6;
  int b = bh >> 2, hd = bh & 3;
  int t = threadIdx.x;
  float T = temp[0];
  for (int i = t; i < 1024; i += 256){
    int c = i >> 5, d = i & 31;
    float nqv = fmaxf(sqrtf(Qn[bh * 32 + c]), 1e-12f);
    float nkv = fmaxf(sqrtf(Kn[bh * 32 + d]), 1e-12f);
    at[i] = fmaxf(S[bh * 1024 + i] / (nqv * nkv) * T, 0.f);
  }
  __syncthreads();
  int n = tile * 256 + t;
  const unsigned short* vb = qkv + (size_t)b * cP * cC3 + (size_t)n * cC3 + 256 + hd * 32;
  float vr[32];
  #pragma unroll
  for (int d8 = 0; d8 < 32; d8 += 8){
    short8 v = *(const short8*)(vb + d8);
    #pragma unroll
    for (int e = 0; e < 8; e++) vr[d8 + e] = bfu2f((unsigned short)v[e]);
  }
  unsigned short* ob = out + (size_t)b * cP * cC + (size_t)n * cC + hd * 32;
  #pragma unroll
  for (int c8 = 0; c8 < 32; c8 += 8){
    short8 ov;
    #pragma unroll
    for (int e = 0; e < 8; e++){
      const float* ar = &at[(c8 + e) * 32];
      float acc = 0.f;
      #pragma unroll
      for (int d = 0; d < 32; d += 4){
        float4 a4 = *(const float4*)(ar + d);
        acc += a4.x * vr[d] + a4.y * vr[d+1] + a4.z * vr[d+2] + a4.w * vr[d+3];
      }
      ov[e] = (short)f2b(acc);
    }
    *(short8*)(ob + c8) = ov;
  }
}

extern "C" void kernel_launch(void* const* d_in, const int* in_sizes, int n_in,
                              void* d_out, int out_size, void* d_ws, size_t ws_size,
                              hipStream_t stream){
  const float* x     = (const float*)d_in[0];
  const float* w_s0  = (const float*)d_in[1];
  const float* b_s0  = (const float*)d_in[2];
  const float* w_s2  = (const float*)d_in[3];
  const float* b_s2  = (const float*)d_in[4];
  const float* rsa_qkv  = (const float*)d_in[5];
  const float* rsa_dw   = (const float*)d_in[6];
  const float* rsa_proj = (const float*)d_in[7];
  const float* rsa_temp = (const float*)d_in[8];
  const float* ffs_in   = (const float*)d_in[9];
  const float* ffs_dw   = (const float*)d_in[10];
  const float* ffs_out  = (const float*)d_in[11];
  const float* w_c0  = (const float*)d_in[12];
  const float* b_c0  = (const float*)d_in[13];
  const float* w_c2  = (const float*)d_in[14];
  const float* b_c2  = (const float*)d_in[15];
  const float* gsa_qkv  = (const float*)d_in[16];
  const float* gsa_dw   = (const float*)d_in[17];
  const float* gsa_proj = (const float*)d_in[18];
  const float* gsa_temp = (const float*)d_in[19];
  const float* ffc_in   = (const float*)d_in[20];
  const float* ffc_dw   = (const float*)d_in[21];
  const float* ffc_out  = (const float*)d_in[22];

  const size_t szC  = (size_t)cB * cC * cP;
  const size_t szC3 = (size_t)cB * cC3 * cP;
  float* XF = (float*)d_ws;                       // x2 fp32 [c][p]
  float* XS = XF + szC;                           // x_ fp32 [c][p]
  unsigned short* LO   = (unsigned short*)(XS + szC);
  unsigned short* Abuf = LO + szC;
  unsigned short* Bbuf = Abuf + szC3;
  float* S  = (float*)(Bbuf + szC3);
  float* Qn = S + 8192;
  float* Kn = Qn + 256;
  float* AT = Kn + 256;
  unsigned short* WB = (unsigned short*)(AT + 1024);
  unsigned short* W_QKV_S = WB;
  unsigned short* W_QKV_C = WB + 49152;
  unsigned short* W_FIN_S = WB + 98304;
  unsigned short* W_FIN_C = WB + 147456;
  unsigned short* W_PRJ_S = WB + 196608;
  unsigned short* W_PRJ_C = WB + 212992;
  unsigned short* W_FO_S  = WB + 229376;
  unsigned short* W_FO_C  = WB + 274432;

  dim3 t256(256);
  dim3 gLN(cB * cP / 256);
  dim3 gG3(cP / 128, 3, cB);
  dim3 gG64(cP / 64, 1, cB);
  dim3 gDW(cP / 16, 3, cB);

  k_wcvt<<<dim3(1282), t256, 0, stream>>>(rsa_qkv, gsa_qkv, ffs_in, ffc_in,
                                          rsa_proj, gsa_proj, ffs_out, ffc_out, WB, S);

  // ---------------- spatial (RSA) block ----------------
  k_ln<<<gLN, t256, 0, stream>>>(x, w_s0, b_s0, LO, 126, 126);
  k_gemm<<<gG3, t256, 0, stream>>>(W_QKV_S, LO, Abuf, 128, 128, 384);
  k_dw<0,384,384><<<gDW, t256, 0, stream>>>(Abuf, rsa_dw, Bbuf);
  k_rsa<<<dim3(cB * cNW), t256, 0, stream>>>(Bbuf, rsa_temp, LO);
  k_gemm64<1><<<gG64, t256, 0, stream>>>(W_PRJ_S, LO, nullptr, x, w_s2, b_s2, XS, LO, 128, 128);
  k_gemm<<<gG3, t256, 0, stream>>>(W_FIN_S, LO, Abuf, 128, 128, 352);
  k_dw<1,340,352><<<gDW, t256, 0, stream>>>(Abuf, ffs_dw, Bbuf);
  k_gemm64<2><<<gG64, t256, 0, stream>>>(W_FO_S, Bbuf, XS, nullptr, w_c0, b_c0, XF, LO, 352, 352);

  // ---------------- channel (GSA) block ----------------
  k_gemm<<<gG3, t256, 0, stream>>>(W_QKV_C, LO, Abuf, 128, 128, 384);
  k_dw<0,384,384><<<gDW, t256, 0, stream>>>(Abuf, gsa_dw, Bbuf);
  k_gram<<<dim3(1024), t256, 0, stream>>>(Bbuf, S, Qn, Kn);
  k_apply<<<dim3(512), t256, 0, stream>>>(Bbuf, S, Qn, Kn, gsa_temp, LO);
  k_gemm64<1><<<gG64, t256, 0, stream>>>(W_PRJ_C, LO, nullptr, XF, w_c2, b_c2, XS, LO, 128, 128);
  k_gemm<<<gG3, t256, 0, stream>>>(W_FIN_C, LO, Abuf, 128, 128, 352);
  k_dw<1,340,352><<<gDW, t256, 0, stream>>>(Abuf, ffc_dw, Bbuf);
  k_gemm64<3><<<gG64, t256, 0, stream>>>(W_FO_C, Bbuf, XS, nullptr, nullptr, nullptr,
                                         (float*)d_out, nullptr, 352, 352);
}

// Round 14
// 361.380 us; speedup vs baseline: 1.1948x; 1.0023x over previous
//
#include <hip/hip_runtime.h>
#include <hip/hip_bf16.h>
#include <math.h>

typedef __hip_bfloat16 bf16;
typedef __attribute__((ext_vector_type(8))) short short8;
typedef __attribute__((ext_vector_type(4))) short short4v;
typedef __attribute__((ext_vector_type(4))) float float4v;

static constexpr int cB  = 2;
static constexpr int cC  = 128;
static constexpr int cH  = 128;
static constexpr int cW  = 128;
static constexpr int cP  = cH * cW;       // 16384
static constexpr int cC3 = 384;
static constexpr int cHID = 340;
static constexpr int cNW = 1024;
static constexpr float cEPS = 1e-6f;

__device__ __forceinline__ float bfu2f(unsigned short u){
  union { unsigned int i; float f; } c; c.i = ((unsigned int)u) << 16; return c.f;
}
__device__ __forceinline__ unsigned short f2b(float f){
  union { float f; unsigned int u; } c; c.f = f;
  unsigned int r = c.u + 0x7FFFu + ((c.u >> 16) & 1u);
  return (unsigned short)(r >> 16);
}

// ---- convert all 8 weight matrices fp32 -> bf16 (with padding) into WB; tail zeroes S
__global__ void k_wcvt(const float* __restrict__ qkv_s, const float* __restrict__ qkv_c,
                       const float* __restrict__ fin_s, const float* __restrict__ fin_c,
                       const float* __restrict__ prj_s, const float* __restrict__ prj_c,
                       const float* __restrict__ fo_s,  const float* __restrict__ fo_c,
                       unsigned short* __restrict__ WB, float* __restrict__ S){
  int i = blockIdx.x * 256 + threadIdx.x;
  if (i >= 319488){
    int j = i - 319488;
    if (j < 8704) S[j] = 0.f;
    return;
  }
  float v;
  if (i < 98304){
    v = (i < 49152) ? qkv_s[i] : qkv_c[i - 49152];
  } else if (i < 196608){
    int j = (i < 147456) ? (i - 98304) : (i - 147456);
    int row = j >> 7, col = j & 127;
    const float* src = (i < 147456) ? fin_s : fin_c;
    v = (row < cHID) ? src[row * 128 + col] : 0.f;
  } else if (i < 229376){
    v = (i < 212992) ? prj_s[i - 196608] : prj_c[i - 212992];
  } else {
    int j = (i < 274432) ? (i - 229376) : (i - 274432);
    int row = j / 352, col = j - row * 352;
    const float* src = (i < 274432) ? fo_s : fo_c;
    v = (col < cHID) ? src[row * cHID + col] : 0.f;
  }
  WB[i] = f2b(v);
}

// ---- standalone LayerNorm (first LN only): fp32 [c][p] -> bf16 [p][128], roll shift
__global__ void __launch_bounds__(256) k_ln(const float* __restrict__ a,
                                            const float* __restrict__ gamma,
                                            const float* __restrict__ beta,
                                            unsigned short* __restrict__ out, int sh, int sw){
  int idx = blockIdx.x * 256 + threadIdx.x;
  if (idx >= cB * cP) return;
  int b = idx >> 14;
  int p = idx & (cP - 1);
  const float* ap = a + (size_t)b * cC * cP + p;
  float s = 0.f, ss = 0.f;
  #pragma unroll 8
  for (int c = 0; c < cC; c++){
    float v = ap[c * cP];
    s += v; ss += v * v;
  }
  float m = s * (1.f / cC);
  float var = ss * (1.f / cC) - m * m;
  float rstd = rsqrtf(var + cEPS);
  int h = p >> 7, w = p & 127;
  int h2 = (h + sh) & (cH - 1);
  int w2 = (w + sw) & (cW - 1);
  unsigned short* op = out + (size_t)b * cP * cC + (size_t)(h2 * cW + w2) * cC;
  #pragma unroll
  for (int c8 = 0; c8 < cC; c8 += 8){
    short8 tv;
    #pragma unroll
    for (int j = 0; j < 8; j++){
      float v = ap[(c8 + j) * cP];
      tv[j] = (short)f2b((v - m) * rstd * gamma[c8 + j] + beta[c8 + j]);
    }
    *(short8*)(op + c8) = tv;
  }
}

// ---- MFMA GEMM: 64px x 128m tile, r11 K-loop staging (streamed W), bf16 out [p][m] ----
__global__ void __launch_bounds__(256) k_gemm(const unsigned short* __restrict__ Wb,
                                              const unsigned short* __restrict__ Xg,
                                              unsigned short* __restrict__ Out,
                                              int K, int PK, int PM){
  __shared__ short Wls[128 * 40];
  __shared__ short Xls[64 * 40];
  int b  = blockIdx.z;
  int p0 = blockIdx.x * 64;
  int m0 = blockIdx.y * 128;
  int t  = threadIdx.x;
  int lanelo = t & 15;
  int quad   = (t >> 4) & 3;
  int wv = t >> 6;
  int w1 = wv & 1;          // px half (32)
  int w2 = wv >> 1;         // m half (64)
  int srw = t >> 1;
  int kow = (t & 1) * 16;
  int srx = t >> 2;
  int kox = (t & 3) * 8;

  float4v acc[2][4];
  #pragma unroll
  for (int i = 0; i < 2; i++)
    #pragma unroll
    for (int j = 0; j < 4; j++)
      acc[i][j] = (float4v){0.f, 0.f, 0.f, 0.f};

  const unsigned short* Xb = Xg + (size_t)b * cP * PK;

  for (int k0 = 0; k0 < K; k0 += 32){
    short8 xv  = *(const short8*)(Xb + (size_t)(p0 + srx) * PK + k0 + kox);
    short8 wv0 = *(const short8*)(Wb + (size_t)(m0 + srw) * K + k0 + kow);
    short8 wv1 = *(const short8*)(Wb + (size_t)(m0 + srw) * K + k0 + kow + 8);
    __syncthreads();
    *(short8*)&Wls[srw * 40 + kow]     = wv0;
    *(short8*)&Wls[srw * 40 + kow + 8] = wv1;
    *(short8*)&Xls[srx * 40 + kox]     = xv;
    __syncthreads();
    short8 af[2], bfr[4];
    #pragma unroll
    for (int i = 0; i < 2; i++)
      af[i] = *(const short8*)&Xls[(w1 * 32 + i * 16 + lanelo) * 40 + quad * 8];
    #pragma unroll
    for (int j = 0; j < 4; j++)
      bfr[j] = *(const short8*)&Wls[(w2 * 64 + j * 16 + lanelo) * 40 + quad * 8];
    #pragma unroll
    for (int i = 0; i < 2; i++)
      #pragma unroll
      for (int j = 0; j < 4; j++)
        acc[i][j] = __builtin_amdgcn_mfma_f32_16x16x32_bf16(af[i], bfr[j], acc[i][j], 0, 0, 0);
  }
  unsigned short* Ob = Out + (size_t)b * cP * PM;
  #pragma unroll
  for (int i = 0; i < 2; i++)
    #pragma unroll
    for (int j = 0; j < 4; j++){
      int wrow = m0 + w2 * 64 + j * 16 + lanelo;
      if (wrow >= PM) continue;
      #pragma unroll
      for (int r = 0; r < 4; r++){
        int pix = p0 + w1 * 32 + i * 16 + quad * 4 + r;
        Ob[(size_t)pix * PM + wrow] = f2b(acc[i][j][r]);
      }
    }
}

// ---- MFMA GEMM 64px x 128m (M=128) with fused epilogue.
// MODE 1: Tr = acc; LN(Base + acc) -> LNo   (proj+LN)
// MODE 2: Tr = acc + R; LN(Tr) -> LNo       (ffn_out+LN)
// MODE 3: Tr = acc + R; no LN               (final ffc_out)
template<int MODE>
__global__ void __launch_bounds__(256) k_gemm64(const unsigned short* __restrict__ Wb,
                                                const unsigned short* __restrict__ Xg,
                                                const float* __restrict__ R,
                                                const float* __restrict__ Base,
                                                const float* __restrict__ gamma,
                                                const float* __restrict__ beta,
                                                float* __restrict__ Tr,
                                                unsigned short* __restrict__ LNo,
                                                int K, int PK){
  __shared__ short SMEM[8704];
  __shared__ float gls[128], bls[128];
  __shared__ float psum[64], pssq[64];
  short* Wls = SMEM;
  short* Xls = SMEM + 5120;
  int b  = blockIdx.z;
  int p0 = blockIdx.x * 64;
  int t  = threadIdx.x;
  int lanelo = t & 15;
  int quad   = (t >> 4) & 3;
  int wv = t >> 6;
  int w2 = wv >> 1, w1 = wv & 1;
  int srw = t >> 1;
  int kow = (t & 1) * 16;
  int srx = t >> 2;
  int kox = (t & 3) * 8;

  if (MODE != 3){
    if (t < 128){ gls[t] = gamma[t]; bls[t] = beta[t]; }
    if (t < 64){ psum[t] = 0.f; pssq[t] = 0.f; }
  }

  float4v acc[4][2];
  #pragma unroll
  for (int i = 0; i < 4; i++){
    acc[i][0] = (float4v){0.f, 0.f, 0.f, 0.f};
    acc[i][1] = (float4v){0.f, 0.f, 0.f, 0.f};
  }
  const unsigned short* Xb = Xg + (size_t)b * cP * PK;

  for (int k0 = 0; k0 < K; k0 += 32){
    short8 xv = *(const short8*)(Xb + (size_t)(p0 + srx) * PK + k0 + kox);
    short8 wv0 = *(const short8*)(Wb + (size_t)srw * K + k0 + kow);
    short8 wv1 = *(const short8*)(Wb + (size_t)srw * K + k0 + kow + 8);
    __syncthreads();
    *(short8*)&Wls[srw * 40 + kow]     = wv0;
    *(short8*)&Wls[srw * 40 + kow + 8] = wv1;
    *(short8*)&Xls[srx * 40 + kox]     = xv;
    __syncthreads();
    short8 af[4], bfr[2];
    #pragma unroll
    for (int i = 0; i < 4; i++)
      af[i] = *(const short8*)&Wls[(w2 * 64 + i * 16 + lanelo) * 40 + quad * 8];
    #pragma unroll
    for (int j = 0; j < 2; j++)
      bfr[j] = *(const short8*)&Xls[(w1 * 32 + j * 16 + lanelo) * 40 + quad * 8];
    #pragma unroll
    for (int i = 0; i < 4; i++)
      #pragma unroll
      for (int j = 0; j < 2; j++)
        acc[i][j] = __builtin_amdgcn_mfma_f32_16x16x32_bf16(af[i], bfr[j], acc[i][j], 0, 0, 0);
  }
  float lnv[4][2][4];
  #pragma unroll
  for (int i = 0; i < 4; i++)
    #pragma unroll
    for (int j = 0; j < 2; j++){
      int n = p0 + w1 * 32 + j * 16 + lanelo;
      #pragma unroll
      for (int r = 0; r < 4; r++){
        int m = w2 * 64 + i * 16 + quad * 4 + r;
        size_t idx = (size_t)b * cC * cP + (size_t)m * cP + n;
        float v = acc[i][j][r];
        if (MODE >= 2) v += R[idx];
        Tr[idx] = v;
        if (MODE == 1) v += Base[idx];
        lnv[i][j][r] = v;
      }
    }
  if (MODE == 3) return;
  __syncthreads();
  #pragma unroll
  for (int j = 0; j < 2; j++){
    int nl = w1 * 32 + j * 16 + lanelo;
    float s = 0.f, ss = 0.f;
    #pragma unroll
    for (int i = 0; i < 4; i++)
      #pragma unroll
      for (int r = 0; r < 4; r++){
        float v = lnv[i][j][r];
        s += v; ss += v * v;
      }
    atomicAdd(&psum[nl], s);
    atomicAdd(&pssq[nl], ss);
  }
  __syncthreads();
  #pragma unroll
  for (int j = 0; j < 2; j++){
    int nl = w1 * 32 + j * 16 + lanelo;
    float mean = psum[nl] * (1.f / cC);
    float var = pssq[nl] * (1.f / cC) - mean * mean;
    float rstd = rsqrtf(var + cEPS);
    #pragma unroll
    for (int i = 0; i < 4; i++)
      #pragma unroll
      for (int r = 0; r < 4; r++){
        int m = w2 * 64 + i * 16 + quad * 4 + r;
        SMEM[nl * 136 + m] = (short)f2b((lnv[i][j][r] - mean) * rstd * gls[m] + bls[m]);
      }
  }
  __syncthreads();
  unsigned short* Ob = LNo + (size_t)b * cP * cC;
  #pragma unroll
  for (int rr = 0; rr < 4; rr++){
    int id = t + rr * 256;
    int row = id >> 4, col8 = (id & 15) * 8;
    short8 sv = *(const short8*)&SMEM[row * 136 + col8];
    *(short8*)(Ob + (size_t)(p0 + row) * cC + col8) = sv;
  }
}

// ---- depthwise 3x3 SAME, [p][c] layout, optional exact gelu ----
template<int GELU, int CCn, int PITCH>
__global__ void __launch_bounds__(256) k_dw(const unsigned short* __restrict__ in,
                                            const float* __restrict__ wt,
                                            unsigned short* __restrict__ out){
  __shared__ float wls[16 * 76];
  int t = threadIdx.x;
  int cbase = blockIdx.y * 128;
  for (int i = t; i < 16 * 72; i += 256){
    int cg = i / 72, rem = i - cg * 72;     // rem = tap*8 + j
    int tap = rem >> 3, j = rem & 7;
    int c = cbase + cg * 8 + j;
    wls[cg * 76 + rem] = (c < CCn) ? wt[c * 9 + tap] : 0.f;
  }
  __syncthreads();
  int cgl = t & 15, pixl = t >> 4;
  int c0 = cbase + cgl * 8;
  if (c0 >= PITCH) return;
  int p = blockIdx.x * 16 + pixl;
  int h = p >> 7, w = p & 127;
  int b = blockIdx.z;
  const unsigned short* ib = in + (size_t)b * cP * PITCH;
  float4 wreg[18];
  #pragma unroll
  for (int q = 0; q < 18; q++)
    wreg[q] = *(const float4*)&wls[cgl * 76 + q * 4];
  short8 v[9];
  #pragma unroll
  for (int ky = 0; ky < 3; ky++){
    int hh = h + ky - 1;
    bool okh = (unsigned)hh < (unsigned)cH;
    int hc = okh ? hh : h;
    #pragma unroll
    for (int kx = 0; kx < 3; kx++){
      int ww = w + kx - 1;
      bool okw = (unsigned)ww < (unsigned)cW;
      int wc = okw ? ww : w;
      short8 lv = *(const short8*)(ib + (size_t)(hc * cW + wc) * PITCH + c0);
      if (!(okh && okw)) lv = (short8){0,0,0,0,0,0,0,0};
      v[ky * 3 + kx] = lv;
    }
  }
  float acc[8] = {0,0,0,0,0,0,0,0};
  #pragma unroll
  for (int tap = 0; tap < 9; tap++){
    float4 w0 = wreg[tap * 2];
    float4 w1 = wreg[tap * 2 + 1];
    float wa[8] = {w0.x, w0.y, w0.z, w0.w, w1.x, w1.y, w1.z, w1.w};
    #pragma unroll
    for (int j = 0; j < 8; j++)
      acc[j] += wa[j] * bfu2f((unsigned short)v[tap][j]);
  }
  short8 ov;
  #pragma unroll
  for (int j = 0; j < 8; j++){
    float vv = acc[j];
    if (GELU) vv = 0.5f * vv * (1.f + erff(vv * 0.70710678118654752f));
    ov[j] = (short)f2b(vv);
  }
  *(short8*)(out + (size_t)b * cP * PITCH + (size_t)p * PITCH + c0) = ov;
}

// ---- RSA window attention via MFMA ----
__global__ void __launch_bounds__(256) k_rsa(const unsigned short* __restrict__ qkv,
                                             const float* __restrict__ temp,
                                             unsigned short* __restrict__ out){
  constexpr int QT = 0;
  constexpr int KT = 5120;
  constexpr int VO = 10240;
  constexpr int AT = 12416;
  __shared__ short lds[21632];
  __shared__ float nq[16], nk[16];
  int blk = blockIdx.x;
  int b  = blk >> 10;
  int nw = blk & 1023;
  int hb = nw >> 5, wb = nw & 31;
  int t = threadIdx.x;
  #pragma unroll
  for (int j = 0; j < 5; j++)
    *(short8*)&lds[t * 40 + j * 8] = (short8){0,0,0,0,0,0,0,0};
  if (t < 16) nq[t] = 0.f;
  else if (t < 32) nk[t - 16] = 0.f;
  __syncthreads();
  const unsigned short* base = qkv + (size_t)b * cP * cC3;
  #pragma unroll
  for (int r = 0; r < 3; r++){
    int i = t + 256 * r;
    int pix = i / 48;
    int cg = i - pix * 48;
    int c0 = cg * 8;
    int gp = (hb * 4 + (pix >> 2)) * cW + wb * 4 + (pix & 3);
    short8 v = *(const short8*)(base + (size_t)gp * cC3 + c0);
    if (c0 < 256){
      float s = 0.f;
      #pragma unroll
      for (int e = 0; e < 8; e++){ float f = bfu2f((unsigned short)v[e]); s += f * f; }
      int off = (c0 < 128) ? (QT + c0 * 40) : (KT + (c0 - 128) * 40);
      #pragma unroll
      for (int e = 0; e < 8; e++) lds[off + e * 40 + pix] = v[e];
      atomicAdd((c0 < 128) ? &nq[pix] : &nk[pix], s);
    } else {
      *(short8*)&lds[VO + pix * 136 + (c0 - 256)] = v;
    }
  }
  __syncthreads();
  float T = temp[0];
  #pragma unroll
  for (int r = 0; r < 8; r++){
    int idx = t + 256 * r;
    int c = idx >> 4, p = idx & 15;
    float sc = (1.f / fmaxf(sqrtf(nq[p]), 1e-12f)) * (1.f / fmaxf(sqrtf(nk[p]), 1e-12f));
    int a = QT + c * 40 + p;
    lds[a] = (short)f2b(bfu2f((unsigned short)lds[a]) * sc);
  }
  __syncthreads();
  int lanelo = t & 15;
  int quad = (t >> 4) & 3;
  int wv = t >> 6;
  float4v oacc[2];
  oacc[0] = (float4v){0.f,0.f,0.f,0.f};
  oacc[1] = (float4v){0.f,0.f,0.f,0.f};
  for (int ch = 0; ch < 2; ch++){
    #pragma unroll
    for (int ct = 0; ct < 4; ct++){
      int c0 = ch * 64 + ct * 16;
      short8 af = *(const short8*)&lds[QT + (c0 + lanelo) * 40 + quad * 8];
      #pragma unroll
      for (int dt = 0; dt < 2; dt++){
        int d0 = wv * 32 + dt * 16;
        short8 bf = *(const short8*)&lds[KT + (d0 + lanelo) * 40 + quad * 8];
        float4v acc = __builtin_amdgcn_mfma_f32_16x16x32_bf16(af, bf,
                        (float4v){0.f,0.f,0.f,0.f}, 0, 0, 0);
        short4v sv;
        #pragma unroll
        for (int r2 = 0; r2 < 4; r2++) sv[r2] = (short)f2b(fmaxf(acc[r2] * T, 0.f));
        *(short4v*)&lds[AT + (d0 + lanelo) * 72 + ct * 16 + quad * 4] = sv;
      }
    }
    __syncthreads();
    #pragma unroll
    for (int dt = 0; dt < 2; dt++){
      int d0 = wv * 32 + dt * 16;
      #pragma unroll
      for (int kk = 0; kk < 2; kk++){
        short8 av8 = *(const short8*)&lds[VO + lanelo * 136 + ch * 64 + kk * 32 + quad * 8];
        short8 bv8 = *(const short8*)&lds[AT + (d0 + lanelo) * 72 + kk * 32 + quad * 8];
        oacc[dt] = __builtin_amdgcn_mfma_f32_16x16x32_bf16(av8, bv8, oacc[dt], 0, 0, 0);
      }
    }
    __syncthreads();
  }
  #pragma unroll
  for (int dt = 0; dt < 2; dt++){
    int d = wv * 32 + dt * 16 + lanelo;
    #pragma unroll
    for (int r2 = 0; r2 < 4; r2++){
      int p = quad * 4 + r2;
      int h2 = (hb * 4 + (p >> 2) + 2) & (cH - 1);
      int w2 = (wb * 4 + (p & 3) + 2) & (cW - 1);
      out[(size_t)b * cP * cC + (size_t)(h2 * cW + w2) * cC + d] = f2b(oacc[dt][r2]);
    }
  }
}

// ---- GSA Gram ----
__global__ void __launch_bounds__(256) k_gram(const unsigned short* __restrict__ qkv,
                                              float* __restrict__ S,
                                              float* __restrict__ Qn,
                                              float* __restrict__ Kn){
  __shared__ float qs[32][132];
  __shared__ float ks[32][132];
  int blk = blockIdx.x;
  int chunk = blk & 127;
  int bh = blk >> 7;
  int b = bh >> 2, hd = bh & 3;
  int n0 = chunk * 128;
  int t = threadIdx.x;
  {
    int row = t >> 1;
    int half = t & 1;
    const unsigned short* pq = qkv + (size_t)b * cP * cC3 + (size_t)(n0 + row) * cC3 + hd * 32 + half * 16;
    const unsigned short* pk = pq + 128;
    short8 q0 = *(const short8*)pq;
    short8 q1 = *(const short8*)(pq + 8);
    short8 k0 = *(const short8*)pk;
    short8 k1 = *(const short8*)(pk + 8);
    #pragma unroll
    for (int e = 0; e < 8; e++){
      qs[half * 16 + e][row]     = bfu2f((unsigned short)q0[e]);
      qs[half * 16 + 8 + e][row] = bfu2f((unsigned short)q1[e]);
      ks[half * 16 + e][row]     = bfu2f((unsigned short)k0[e]);
      ks[half * 16 + 8 + e][row] = bfu2f((unsigned short)k1[e]);
    }
  }
  __syncthreads();
  if (t < 64){
    const float* row = (t < 32) ? qs[t] : ks[t - 32];
    float s = 0.f;
    #pragma unroll
    for (int i = 0; i < 128; i += 4){
      float4 v = *(const float4*)(row + i);
      s += v.x*v.x + v.y*v.y + v.z*v.z + v.w*v.w;
    }
    if (t < 32) atomicAdd(&Qn[bh * 32 + t], s);
    else        atomicAdd(&Kn[bh * 32 + (t - 32)], s);
  }
  int cc = (t >> 4) * 2;
  int dd = t & 15;
  float a00 = 0.f, a01 = 0.f, a10 = 0.f, a11 = 0.f;
  for (int n = 0; n < 128; n += 4){
    float4 q0 = *(const float4*)&qs[cc][n];
    float4 q1 = *(const float4*)&qs[cc + 1][n];
    float4 k0 = *(const float4*)&ks[dd][n];
    float4 k1 = *(const float4*)&ks[dd + 16][n];
    a00 += q0.x*k0.x + q0.y*k0.y + q0.z*k0.z + q0.w*k0.w;
    a01 += q0.x*k1.x + q0.y*k1.y + q0.z*k1.z + q0.w*k1.w;
    a10 += q1.x*k0.x + q1.y*k0.y + q1.z*k0.z + q1.w*k0.w;
    a11 += q1.x*k1.x + q1.y*k1.y + q1.z*k1.z + q1.w*k1.w;
  }
  float* Sb = S + (size_t)bh * 1024;
  atomicAdd(&Sb[cc * 32 + dd], a00);
  atomicAdd(&Sb[cc * 32 + dd + 16], a01);
  atomicAdd(&Sb[(cc + 1) * 32 + dd], a10);
  atomicAdd(&Sb[(cc + 1) * 32 + dd + 16], a11);
}

// ---- GSA apply with inlined finalize ----
__global__ void __launch_bounds__(256) k_apply(const unsigned short* __restrict__ qkv,
                                               const float* __restrict__ S,
                                               const float* __restrict__ Qn,
                                               const float* __restrict__ Kn,
                                               const float* __restrict__ temp,
                                               unsigned short* __restrict__ out){
  __shared__ float at[1024];
  int blk = blockIdx.x;
  int tile = blk & 63;
  int bh = blk >> 6;
  int b = bh >> 2, hd = bh & 3;
  int t = threadIdx.x;
  float T = temp[0];
  for (int i = t; i < 1024; i += 256){
    int c = i >> 5, d = i & 31;
    float nqv = fmaxf(sqrtf(Qn[bh * 32 + c]), 1e-12f);
    float nkv = fmaxf(sqrtf(Kn[bh * 32 + d]), 1e-12f);
    at[i] = fmaxf(S[bh * 1024 + i] / (nqv * nkv) * T, 0.f);
  }
  __syncthreads();
  int n = tile * 256 + t;
  const unsigned short* vb = qkv + (size_t)b * cP * cC3 + (size_t)n * cC3 + 256 + hd * 32;
  float vr[32];
  #pragma unroll
  for (int d8 = 0; d8 < 32; d8 += 8){
    short8 v = *(const short8*)(vb + d8);
    #pragma unroll
    for (int e = 0; e < 8; e++) vr[d8 + e] = bfu2f((unsigned short)v[e]);
  }
  unsigned short* ob = out + (size_t)b * cP * cC + (size_t)n * cC + hd * 32;
  #pragma unroll
  for (int c8 = 0; c8 < 32; c8 += 8){
    short8 ov;
    #pragma unroll
    for (int e = 0; e < 8; e++){
      const float* ar = &at[(c8 + e) * 32];
      float acc = 0.f;
      #pragma unroll
      for (int d = 0; d < 32; d += 4){
        float4 a4 = *(const float4*)(ar + d);
        acc += a4.x * vr[d] + a4.y * vr[d+1] + a4.z * vr[d+2] + a4.w * vr[d+3];
      }
      ov[e] = (short)f2b(acc);
    }
    *(short8*)(ob + c8) = ov;
  }
}

extern "C" void kernel_launch(void* const* d_in, const int* in_sizes, int n_in,
                              void* d_out, int out_size, void* d_ws, size_t ws_size,
                              hipStream_t stream){
  const float* x     = (const float*)d_in[0];
  const float* w_s0  = (const float*)d_in[1];
  const float* b_s0  = (const float*)d_in[2];
  const float* w_s2  = (const float*)d_in[3];
  const float* b_s2  = (const float*)d_in[4];
  const float* rsa_qkv  = (const float*)d_in[5];
  const float* rsa_dw   = (const float*)d_in[6];
  const float* rsa_proj = (const float*)d_in[7];
  const float* rsa_temp = (const float*)d_in[8];
  const float* ffs_in   = (const float*)d_in[9];
  const float* ffs_dw   = (const float*)d_in[10];
  const float* ffs_out  = (const float*)d_in[11];
  const float* w_c0  = (const float*)d_in[12];
  const float* b_c0  = (const float*)d_in[13];
  const float* w_c2  = (const float*)d_in[14];
  const float* b_c2  = (const float*)d_in[15];
  const float* gsa_qkv  = (const float*)d_in[16];
  const float* gsa_dw   = (const float*)d_in[17];
  const float* gsa_proj = (const float*)d_in[18];
  const float* gsa_temp = (const float*)d_in[19];
  const float* ffc_in   = (const float*)d_in[20];
  const float* ffc_dw   = (const float*)d_in[21];
  const float* ffc_out  = (const float*)d_in[22];

  const size_t szC  = (size_t)cB * cC * cP;
  const size_t szC3 = (size_t)cB * cC3 * cP;
  float* XF = (float*)d_ws;                       // x2 fp32 [c][p]
  float* XS = XF + szC;                           // x_ fp32 [c][p]
  unsigned short* LO   = (unsigned short*)(XS + szC);
  unsigned short* Abuf = LO + szC;
  unsigned short* Bbuf = Abuf + szC3;
  float* S  = (float*)(Bbuf + szC3);
  float* Qn = S + 8192;
  float* Kn = Qn + 256;
  float* AT = Kn + 256;
  unsigned short* WB = (unsigned short*)(AT + 1024);
  unsigned short* W_QKV_S = WB;
  unsigned short* W_QKV_C = WB + 49152;
  unsigned short* W_FIN_S = WB + 98304;
  unsigned short* W_FIN_C = WB + 147456;
  unsigned short* W_PRJ_S = WB + 196608;
  unsigned short* W_PRJ_C = WB + 212992;
  unsigned short* W_FO_S  = WB + 229376;
  unsigned short* W_FO_C  = WB + 274432;

  dim3 t256(256);
  dim3 gLN(cB * cP / 256);
  dim3 gG3(cP / 64, 3, cB);    // 64px tiles, 3 m-tiles: 1536 blocks
  dim3 gG64(cP / 64, 1, cB);
  dim3 gDW(cP / 16, 3, cB);

  k_wcvt<<<dim3(1282), t256, 0, stream>>>(rsa_qkv, gsa_qkv, ffs_in, ffc_in,
                                          rsa_proj, gsa_proj, ffs_out, ffc_out, WB, S);

  // ---------------- spatial (RSA) block ----------------
  k_ln<<<gLN, t256, 0, stream>>>(x, w_s0, b_s0, LO, 126, 126);
  k_gemm<<<gG3, t256, 0, stream>>>(W_QKV_S, LO, Abuf, 128, 128, 384);
  k_dw<0,384,384><<<gDW, t256, 0, stream>>>(Abuf, rsa_dw, Bbuf);
  k_rsa<<<dim3(cB * cNW), t256, 0, stream>>>(Bbuf, rsa_temp, LO);
  k_gemm64<1><<<gG64, t256, 0, stream>>>(W_PRJ_S, LO, nullptr, x, w_s2, b_s2, XS, LO, 128, 128);
  k_gemm<<<gG3, t256, 0, stream>>>(W_FIN_S, LO, Abuf, 128, 128, 352);
  k_dw<1,340,352><<<gDW, t256, 0, stream>>>(Abuf, ffs_dw, Bbuf);
  k_gemm64<2><<<gG64, t256, 0, stream>>>(W_FO_S, Bbuf, XS, nullptr, w_c0, b_c0, XF, LO, 352, 352);

  // ---------------- channel (GSA) block ----------------
  k_gemm<<<gG3, t256, 0, stream>>>(W_QKV_C, LO, Abuf, 128, 128, 384);
  k_dw<0,384,384><<<gDW, t256, 0, stream>>>(Abuf, gsa_dw, Bbuf);
  k_gram<<<dim3(1024), t256, 0, stream>>>(Bbuf, S, Qn, Kn);
  k_apply<<<dim3(512), t256, 0, stream>>>(Bbuf, S, Qn, Kn, gsa_temp, LO);
  k_gemm64<1><<<gG64, t256, 0, stream>>>(W_PRJ_C, LO, nullptr, XF, w_c2, b_c2, XS, LO, 128, 128);
  k_gemm<<<gG3, t256, 0, stream>>>(W_FIN_C, LO, Abuf, 128, 128, 352);
  k_dw<1,340,352><<<gDW, t256, 0, stream>>>(Abuf, ffc_dw, Bbuf);
  k_gemm64<3><<<gG64, t256, 0, stream>>>(W_FO_C, Bbuf, XS, nullptr, nullptr, nullptr,
                                         (float*)d_out, nullptr, 352, 352);
}